// Round 9
// baseline (715.885 us; speedup 1.0000x reference)
//
#include <hip/hip_runtime.h>
#include <hip/hip_cooperative_groups.h>

namespace cg = cooperative_groups;

#define NB 256
#define NO 10
#define NI 1152
#define NK 8
#define ND 16
#define PCH 72    // chunks for pass0/acc (PIC=16)
#define PIC 16
#define DCH 144   // chunks for dotsoft (DIC=8)
#define DIC 8
#define NBLK 512  // coop grid: 2 blocks/CU x 256 CUs guaranteed by __launch_bounds__(256,2)

typedef unsigned short u16;
typedef unsigned int u32;
typedef __attribute__((ext_vector_type(8))) short s8v;   // 8 bf16 = 4 VGPR (MFMA A/B frag)
typedef __attribute__((ext_vector_type(4))) float f4v;   // MFMA C/D frag
typedef __attribute__((ext_vector_type(4))) u32 u32x4;

__device__ __forceinline__ u16 f2bf(float f){
  u32 u = __float_as_uint(f);
  return (u16)((u + 0x7FFFu + ((u >> 16) & 1u)) >> 16);  // RNE
}
__device__ __forceinline__ float bf2f(u16 h){ return __uint_as_float(((u32)h) << 16); }
__device__ __forceinline__ u32 cvt_pk_bf16(float lo, float hi){
  u32 r;
  asm("v_cvt_pk_bf16_f32 %0, %1, %2" : "=v"(r) : "v"(lo), "v"(hi));
  return r;
}
__device__ __forceinline__ s8v zero8(){
  s8v z;
  #pragma unroll
  for (int j = 0; j < 8; ++j) z[j] = 0;
  return z;
}

// ---- phase bodies (identical math to the verified round-6 kernels) ----
// Each takes a work-block index wb; callers map blockIdx or grid-stride onto wb.

__device__ __forceinline__ void prep_body(int t, int stride,
                                          const float* __restrict__ x,
                                          const float* __restrict__ W,
                                          u16* __restrict__ xbf,
                                          u16* __restrict__ Wb,
                                          u16* __restrict__ WTb){
  const int NX = NI * NB * NK;
  for (int idx = t; idx < NX; idx += stride){
    int k = idx & 7, b = (idx >> 3) & (NB - 1), i = idx >> 11;   // NB*NK = 2048
    xbf[idx] = f2bf(x[((size_t)b * NI + i) * NK + k]);
  }
  const int NW = NO * NI * ND * NK;
  for (int idx = t; idx < NW; idx += stride){
    u16 h = f2bf(W[idx]);
    Wb[idx] = h;
    int k = idx & 7, d = (idx >> 3) & 15, oi = idx >> 7;
    WTb[((size_t)oi * NK + k) * ND + d] = h;
  }
}

__device__ __forceinline__ void pass0_body(int wb, int tid,
                                           const u16* __restrict__ xbf,
                                           const u16* __restrict__ Wb,
                                           float* __restrict__ usq,
                                           float* __restrict__ P){
  int ch = wb % PCH, o = wb / PCH, i0 = ch * PIC;
  int w = tid >> 6, l = tid & 63, g = l >> 4, col = l & 15;
  float s0[4][4];
  #pragma unroll
  for (int bt = 0; bt < 4; ++bt){
    #pragma unroll
    for (int j = 0; j < 4; ++j) s0[bt][j] = 0.f;
  }
  for (int ii = 0; ii < PIC; ++ii){
    int i = i0 + ii;
    s8v a = zero8();
    if (g == 0)  // A[d=col][k=j]
      a = *(const s8v*)(Wb + ((size_t)(o * NI + i) * ND + col) * NK);
    #pragma unroll
    for (int bt = 0; bt < 4; ++bt){
      int b = (w * 4 + bt) * 16 + col;
      s8v bf = zero8();
      if (g == 0)  // B[k=j][n=col] = x[i][b][j] (contiguous in b)
        bf = *(const s8v*)(xbf + ((size_t)i * NB + b) * NK);
      f4v c = {0.f, 0.f, 0.f, 0.f};
      c = __builtin_amdgcn_mfma_f32_16x16x32_bf16(a, bf, c, 0, 0, 0);
      float uq = c[0]*c[0] + c[1]*c[1] + c[2]*c[2] + c[3]*c[3];
      uq += __shfl_xor(uq, 16);
      uq += __shfl_xor(uq, 32);
      if (g == 0) usq[((size_t)o * NI + i) * NB + b] = uq;
      #pragma unroll
      for (int j = 0; j < 4; ++j) s0[bt][j] += c[j];
    }
  }
  #pragma unroll
  for (int bt = 0; bt < 4; ++bt){
    int b = (w * 4 + bt) * 16 + col;
    #pragma unroll
    for (int j = 0; j < 4; ++j)
      P[(((size_t)o * ND + (4 * g + j)) * PCH + ch) * NB + b] = 0.1f * s0[bt][j];
  }
}

template<bool LAST>
__device__ __forceinline__ void red_body(int wb, int tid,
                                         const float* __restrict__ P,
                                         u16* __restrict__ Sbt,
                                         float* __restrict__ S){
  int o = wb % NO, d = wb / NO, b = tid;
  const float* p = P + ((size_t)o * ND + d) * PCH * NB + b;
  float a0 = 0.f, a1 = 0.f, a2 = 0.f, a3 = 0.f;
  #pragma unroll
  for (int ch = 0; ch < PCH; ch += 4){
    a0 += p[(size_t)ch * NB];
    a1 += p[(size_t)(ch + 1) * NB];
    a2 += p[(size_t)(ch + 2) * NB];
    a3 += p[(size_t)(ch + 3) * NB];
  }
  float a = (a0 + a1) + (a2 + a3);
  if (LAST) S[((size_t)o * ND + d) * NB + b] = a;
  else      Sbt[((size_t)o * NB + b) * ND + d] = f2bf(a);
}

template<bool FIRST>
__device__ __forceinline__ void dotsoft_body(int wb, int tid,
                                             const u16* __restrict__ xbf,
                                             const u16* __restrict__ WTb,
                                             const u16* __restrict__ Sbt,
                                             const float* __restrict__ usq,
                                             float* __restrict__ L,
                                             float* __restrict__ C){
  int ch = wb % DCH, yy = wb / DCH, ibase = ch * DIC;
  int w = tid >> 6, l = tid & 63, g = l >> 4, col = l & 15;
  int b = (yy * 4 + w) * 16 + col;
  // Hoist B-frags (S tiles); |S|^2 from the frags via shfl (g0:d0-7, g1:d8-15)
  s8v sb[NO];
  float s2v[NO];
  #pragma unroll
  for (int o = 0; o < NO; ++o){
    sb[o] = zero8();
    if (g < 2)
      sb[o] = *(const s8v*)(Sbt + ((size_t)o * NB + b) * ND + 8 * g);
    float s2 = 0.f;
    #pragma unroll
    for (int j = 0; j < 8; ++j){
      float v = bf2f((u16)sb[o][j]);
      s2 = fmaf(v, v, s2);
    }
    s2 += __shfl_xor(s2, 16);
    s2 += __shfl_xor(s2, 32);
    s2v[o] = s2;
  }
  for (int ip = 0; ip < DIC / 2; ++ip){
    int i0 = ibase + 2 * ip;
    int i = i0 + (g >> 1);          // this lane's i for epilogue rows
    int kb = 4 * (g & 1);
    ushort4 xq = *(const ushort4*)(xbf + ((size_t)i * NB + b) * NK + kb);
    float dots[NO];
    #pragma unroll
    for (int o = 0; o < NO; ++o){
      s8v a = zero8();
      if (g < 2){                   // A[r=col][kd=8g+j] = WTb[o][i(r)][k(r)][d]
        int ia = i0 + (col >> 3), ka = col & 7;
        a = *(const s8v*)(WTb + (((size_t)(o * NI + ia)) * NK + ka) * ND + 8 * g);
      }
      f4v c = {0.f, 0.f, 0.f, 0.f};
      c = __builtin_amdgcn_mfma_f32_16x16x32_bf16(a, sb[o], c, 0, 0, 0);
      // C rows 4g+j = (i = i0 + (row>>3), k = row&7); matches (i, kb..kb+3)
      float p = c[0] * bf2f(xq.x) + c[1] * bf2f(xq.y)
              + c[2] * bf2f(xq.z) + c[3] * bf2f(xq.w);
      p += __shfl_xor(p, 16);       // g0+g1 -> dot(i0); g2+g3 -> dot(i1)
      dots[o] = p;
    }
    float lg[NO];
    #pragma unroll
    for (int o = 0; o < NO; ++o){
      float us = usq[((size_t)o * NI + i) * NB + b];
      float t2 = fmaxf(s2v[o] - 2.f * dots[o] + us, 0.f);
      float ut = dots[o] - us;
      float db = (t2 / (1.f + t2)) * ut / (sqrtf(t2) + 1e-8f);
      float lo = FIRST ? db : (L[((size_t)o * NI + i) * NB + b] + db);
      if (FIRST && ((g & 1) == 0)) L[((size_t)o * NI + i) * NB + b] = lo;
      lg[o] = lo;
    }
    float m = lg[0];
    #pragma unroll
    for (int o = 1; o < NO; ++o) m = fmaxf(m, lg[o]);
    float den = 0.f;
    #pragma unroll
    for (int o = 0; o < NO; ++o){ lg[o] = __expf(lg[o] - m); den += lg[o]; }
    float inv = 1.f / den;
    if ((g & 1) == 0){
      #pragma unroll
      for (int o = 0; o < NO; ++o)
        C[((size_t)o * NI + i) * NB + b] = lg[o] * inv;
    }
  }
}

__device__ __forceinline__ void acc_body(int wb, int tid,
                                         const u16* __restrict__ xbf,
                                         const u16* __restrict__ Wb,
                                         const float* __restrict__ C,
                                         float* __restrict__ P){
  int ch = wb % PCH, o = wb / PCH, i0 = ch * PIC;
  int w = tid >> 6, l = tid & 63, g = l >> 4, col = l & 15;
  f4v cacc[4];
  #pragma unroll
  for (int bt = 0; bt < 4; ++bt) cacc[bt] = (f4v){0.f, 0.f, 0.f, 0.f};
  for (int kt = 0; kt < PIC / 4; ++kt){
    int il = i0 + kt * 4 + g;       // this lane's i (K packs 4 i's)
    // A[d=col][k=8g+j] = W[o][il][col][j]
    s8v a = *(const s8v*)(Wb + ((size_t)(o * NI + il) * ND + col) * NK);
    #pragma unroll
    for (int bt = 0; bt < 4; ++bt){
      int b = (w * 4 + bt) * 16 + col;
      float cw = C[((size_t)o * NI + il) * NB + b];
      s8v xv = *(const s8v*)(xbf + ((size_t)il * NB + b) * NK);
      u32x4 q;
      #pragma unroll
      for (int j = 0; j < 4; ++j)
        q[j] = cvt_pk_bf16(bf2f((u16)xv[2*j]) * cw, bf2f((u16)xv[2*j+1]) * cw);
      s8v bb = __builtin_bit_cast(s8v, q);
      cacc[bt] = __builtin_amdgcn_mfma_f32_16x16x32_bf16(a, bb, cacc[bt], 0, 0, 0);
    }
  }
  #pragma unroll
  for (int bt = 0; bt < 4; ++bt){
    int b = (w * 4 + bt) * 16 + col;
    #pragma unroll
    for (int j = 0; j < 4; ++j)
      P[(((size_t)o * ND + (4 * g + j)) * PCH + ch) * NB + b] = cacc[bt][j];
  }
}

__device__ __forceinline__ void final_body(int o, int tid,
                                           const float* __restrict__ S,
                                           float* __restrict__ out){
  int b = tid;
  float s[ND], s2 = 0.f;
  #pragma unroll
  for (int d = 0; d < ND; ++d){
    s[d] = S[((size_t)o * ND + d) * NB + b];
    s2 = fmaf(s[d], s[d], s2);
  }
  float sc = (s2 / (1.f + s2)) / (sqrtf(s2) + 1e-8f);
  #pragma unroll
  for (int d = 0; d < ND; ++d) out[((size_t)b * NO + o) * ND + d] = s[d] * sc;
}

// ---- single cooperative kernel (grid-stride phases + grid.sync) ----

__global__ __launch_bounds__(256, 2) void k_mega(const float* __restrict__ x,
                                                 const float* __restrict__ W,
                                                 float* __restrict__ out,
                                                 u16* __restrict__ xbf,
                                                 u16* __restrict__ Wb,
                                                 u16* __restrict__ WTb,
                                                 float* __restrict__ usq,
                                                 float* __restrict__ L,
                                                 float* __restrict__ C,
                                                 float* __restrict__ P,
                                                 float* __restrict__ S,
                                                 u16* __restrict__ Sbt){
  cg::grid_group grid = cg::this_grid();
  int bid = blockIdx.x, tid = threadIdx.x;

  prep_body(bid * 256 + tid, NBLK * 256, x, W, xbf, Wb, WTb);
  grid.sync();

  // iter 0: uniform c = 0.1 -> partials + usq
  for (int wb = bid; wb < PCH * NO; wb += NBLK) pass0_body(wb, tid, xbf, Wb, usq, P);
  grid.sync();
  for (int wb = bid; wb < NO * ND; wb += NBLK) red_body<false>(wb, tid, P, Sbt, S);
  grid.sync();
  for (int wb = bid; wb < DCH * 4; wb += NBLK) dotsoft_body<true>(wb, tid, xbf, WTb, Sbt, usq, L, C);
  grid.sync();

  // iter 1
  for (int wb = bid; wb < PCH * NO; wb += NBLK) acc_body(wb, tid, xbf, Wb, C, P);
  grid.sync();
  for (int wb = bid; wb < NO * ND; wb += NBLK) red_body<false>(wb, tid, P, Sbt, S);
  grid.sync();
  for (int wb = bid; wb < DCH * 4; wb += NBLK) dotsoft_body<false>(wb, tid, xbf, WTb, Sbt, usq, L, C);
  grid.sync();

  // iter 2 (final accumulation) + squash
  for (int wb = bid; wb < PCH * NO; wb += NBLK) acc_body(wb, tid, xbf, Wb, C, P);
  grid.sync();
  for (int wb = bid; wb < NO * ND; wb += NBLK) red_body<true>(wb, tid, P, Sbt, S);
  grid.sync();
  for (int wb = bid; wb < NO; wb += NBLK) final_body(wb, tid, S, out);
}

// ---- standalone wrappers (fallback path = verified round-6 pipeline) ----

__global__ __launch_bounds__(256) void k_prep(const float* __restrict__ x,
                                              const float* __restrict__ W,
                                              u16* __restrict__ xbf,
                                              u16* __restrict__ Wb,
                                              u16* __restrict__ WTb){
  prep_body(blockIdx.x * 256 + threadIdx.x, gridDim.x * 256, x, W, xbf, Wb, WTb);
}
__global__ __launch_bounds__(256) void k_pass0(const u16* __restrict__ xbf,
                                               const u16* __restrict__ Wb,
                                               float* __restrict__ usq,
                                               float* __restrict__ P){
  pass0_body(blockIdx.y * PCH + blockIdx.x, threadIdx.x, xbf, Wb, usq, P);
}
template<bool LAST>
__global__ __launch_bounds__(256) void k_red(const float* __restrict__ P,
                                             u16* __restrict__ Sbt,
                                             float* __restrict__ S){
  red_body<LAST>(blockIdx.y * NO + blockIdx.x, threadIdx.x, P, Sbt, S);
}
template<bool FIRST>
__global__ __launch_bounds__(256) void k_dotsoft(const u16* __restrict__ xbf,
                                                 const u16* __restrict__ WTb,
                                                 const u16* __restrict__ Sbt,
                                                 const float* __restrict__ usq,
                                                 float* __restrict__ L,
                                                 float* __restrict__ C){
  dotsoft_body<FIRST>(blockIdx.y * DCH + blockIdx.x, threadIdx.x, xbf, WTb, Sbt, usq, L, C);
}
__global__ __launch_bounds__(256) void k_acc(const u16* __restrict__ xbf,
                                             const u16* __restrict__ Wb,
                                             const float* __restrict__ C,
                                             float* __restrict__ P){
  acc_body(blockIdx.y * PCH + blockIdx.x, threadIdx.x, xbf, Wb, C, P);
}
__global__ __launch_bounds__(256) void k_final(const float* __restrict__ S,
                                               float* __restrict__ out){
  final_body(blockIdx.x, threadIdx.x, S, out);
}

extern "C" void kernel_launch(void* const* d_in, const int* in_sizes, int n_in,
                              void* d_out, int out_size, void* d_ws, size_t ws_size,
                              hipStream_t stream){
  const float* x = (const float*)d_in[0];
  // d_in[1] (y) unused by the reference computation.
  const float* W = (const float*)d_in[2];
  float* out = (float*)d_out;
  char* ws = (char*)d_ws;

  const size_t xbf_b = (size_t)NI * NB * NK * sizeof(u16);            // 4.7 MB
  const size_t Wb_b  = (size_t)NO * NI * ND * NK * sizeof(u16);       // 2.95 MB
  const size_t usq_b = (size_t)NO * NI * NB * sizeof(float);          // 11.8 MB
  const size_t P_b   = (size_t)NO * ND * PCH * NB * sizeof(float);    // 11.8 MB
  const size_t S_b   = (size_t)NO * ND * NB * sizeof(float);          // 160 KB
  const size_t Sbt_b = (size_t)NO * NB * ND * sizeof(u16);            // 80 KB

  size_t off = 0;
  u16*   xbf = (u16*)(ws + off);   off += xbf_b;
  u16*   Wb  = (u16*)(ws + off);   off += Wb_b;
  u16*   WTb = (u16*)(ws + off);   off += Wb_b;
  float* usq = (float*)(ws + off); off += usq_b;
  float* L   = (float*)(ws + off); off += usq_b;
  float* C   = (float*)(ws + off); off += usq_b;
  float* P   = (float*)(ws + off); off += P_b;
  float* S   = (float*)(ws + off); off += S_b;
  u16*   Sbt = (u16*)(ws + off);   off += Sbt_b;
  (void)ws_size; (void)in_sizes; (void)n_in; (void)out_size;

  void* args[] = {(void*)&x, (void*)&W, (void*)&out,
                  (void*)&xbf, (void*)&Wb, (void*)&WTb,
                  (void*)&usq, (void*)&L, (void*)&C,
                  (void*)&P, (void*)&S, (void*)&Sbt};
  hipError_t err = hipLaunchCooperativeKernel((const void*)k_mega, dim3(NBLK),
                                              dim3(256), args, 0, stream);
  if (err != hipSuccess){
    // Fallback: verified round-6 multi-kernel pipeline (135.8 us)
    k_prep<<<dim3(1024), 256, 0, stream>>>(x, W, xbf, Wb, WTb);
    k_pass0<<<dim3(PCH, NO), 256, 0, stream>>>(xbf, Wb, usq, P);
    k_red<false><<<dim3(NO, ND), 256, 0, stream>>>(P, Sbt, S);
    k_dotsoft<true><<<dim3(DCH, 4), 256, 0, stream>>>(xbf, WTb, Sbt, usq, L, C);
    k_acc<<<dim3(PCH, NO), 256, 0, stream>>>(xbf, Wb, C, P);
    k_red<false><<<dim3(NO, ND), 256, 0, stream>>>(P, Sbt, S);
    k_dotsoft<false><<<dim3(DCH, 4), 256, 0, stream>>>(xbf, WTb, Sbt, usq, L, C);
    k_acc<<<dim3(PCH, NO), 256, 0, stream>>>(xbf, Wb, C, P);
    k_red<true><<<dim3(NO, ND), 256, 0, stream>>>(P, Sbt, S);
    k_final<<<dim3(NO), 256, 0, stream>>>(S, out);
  }
}

// Round 10
// 133.040 us; speedup vs baseline: 5.3810x; 5.3810x over previous
//
#include <hip/hip_runtime.h>

#define NB 256
#define NO 10
#define NI 1152
#define NK 8
#define ND 16
#define PCH 144   // i-chunks for pass0/dotacc (PIC=8)
#define PIC 8

typedef unsigned short u16;
typedef unsigned int u32;
typedef __attribute__((ext_vector_type(8))) short s8v;   // 8 bf16 (MFMA A/B frag)
typedef __attribute__((ext_vector_type(4))) float f4v;   // MFMA C/D frag

__device__ __forceinline__ float bf2f(u16 h){ return __uint_as_float(((u32)h) << 16); }
__device__ __forceinline__ u32 cvt_pk_bf16(float lo, float hi){
  u32 r;
  asm("v_cvt_pk_bf16_f32 %0, %1, %2" : "=v"(r) : "v"(lo), "v"(hi));
  return r;
}
__device__ __forceinline__ s8v zero8(){
  s8v z;
  #pragma unroll
  for (int j = 0; j < 8; ++j) z[j] = 0;
  return z;
}

// prep: blocks [0,288): x [b][i][k] f32 -> xbf [i][b][k] bf16 via LDS 32x32 tile
//       blocks [288,1008): W [o][i][d][k] -> Wb (same layout) + WTb [o][i][k][d]
__global__ __launch_bounds__(256) void k_prep(const float* __restrict__ x,
                                              const float* __restrict__ W,
                                              u16* __restrict__ xbf,
                                              u16* __restrict__ Wb,
                                              u16* __restrict__ WTb){
  int blk = blockIdx.x;
  if (blk < 288){
    __shared__ __align__(16) u16 tile[32][33][8];
    int i0 = (blk >> 3) * 32, b0 = (blk & 7) * 32;
    int t = threadIdx.x;
    int bl = t >> 3, seg = t & 7;    // phase 1: thread = (b-local, 4-i segment)
    const float* src = x + ((size_t)(b0 + bl) * NI + (i0 + seg * 4)) * NK;
    #pragma unroll
    for (int q = 0; q < 4; ++q){
      float4 v0 = *(const float4*)(src + q * 8);
      float4 v1 = *(const float4*)(src + q * 8 + 4);
      *(uint4*)(&tile[seg * 4 + q][bl][0]) =
        make_uint4(cvt_pk_bf16(v0.x, v0.y), cvt_pk_bf16(v0.z, v0.w),
                   cvt_pk_bf16(v1.x, v1.y), cvt_pk_bf16(v1.z, v1.w));
    }
    __syncthreads();
    int il = t >> 3, sb2 = t & 7;    // phase 2: thread = (i-local, 4-b segment)
    u16* dst = xbf + ((size_t)(i0 + il) * NB + b0 + sb2 * 4) * NK;
    #pragma unroll
    for (int q = 0; q < 4; ++q)
      *(uint4*)(dst + q * 8) = *(const uint4*)(&tile[il][sb2 * 4 + q][0]);
  } else {
    int t = (blk - 288) * 256 + threadIdx.x;   // one (o,i,d) row of 8 k per thread
    if (t < NO * NI * ND){
      int oi = t >> 4, d = t & 15;
      const float* src = W + (size_t)t * NK;
      float4 v0 = *(const float4*)(src);
      float4 v1 = *(const float4*)(src + 4);
      u32 p0 = cvt_pk_bf16(v0.x, v0.y), p1 = cvt_pk_bf16(v0.z, v0.w);
      u32 p2 = cvt_pk_bf16(v1.x, v1.y), p3 = cvt_pk_bf16(v1.z, v1.w);
      *(uint4*)(Wb + (size_t)t * NK) = make_uint4(p0, p1, p2, p3);
      u16 e[8] = {(u16)(p0 & 0xffff), (u16)(p0 >> 16), (u16)(p1 & 0xffff), (u16)(p1 >> 16),
                  (u16)(p2 & 0xffff), (u16)(p2 >> 16), (u16)(p3 & 0xffff), (u16)(p3 >> 16)};
      #pragma unroll
      for (int k = 0; k < 8; ++k)
        WTb[((size_t)oi * NK + k) * ND + d] = e[k];
    }
  }
}

// pass0: u-tiles via MFMA; usq[o,i,b]; Pq[(o*4+g)*PCH+ch][b] = float4(0.1*sum_i u)
__global__ __launch_bounds__(256) void k_pass0(const u16* __restrict__ xbf,
                                               const u16* __restrict__ Wb,
                                               float* __restrict__ usq,
                                               float4* __restrict__ Pq){
  int ch = blockIdx.x, o = blockIdx.y, i0 = ch * PIC;
  int w = threadIdx.x >> 6, l = threadIdx.x & 63, g = l >> 4, col = l & 15;
  float s0[4][4];
  #pragma unroll
  for (int bt = 0; bt < 4; ++bt){
    #pragma unroll
    for (int j = 0; j < 4; ++j) s0[bt][j] = 0.f;
  }
  for (int ii = 0; ii < PIC; ++ii){
    int i = i0 + ii;
    s8v a = zero8();
    if (g == 0)  // A[d=col][k=j]
      a = *(const s8v*)(Wb + ((size_t)(o * NI + i) * ND + col) * NK);
    #pragma unroll
    for (int bt = 0; bt < 4; ++bt){
      int b = (w * 4 + bt) * 16 + col;
      s8v bf = zero8();
      if (g == 0)  // B[k=j][n=col] = x[i][b][j]
        bf = *(const s8v*)(xbf + ((size_t)i * NB + b) * NK);
      f4v c = {0.f, 0.f, 0.f, 0.f};
      c = __builtin_amdgcn_mfma_f32_16x16x32_bf16(a, bf, c, 0, 0, 0);
      float uq = c[0]*c[0] + c[1]*c[1] + c[2]*c[2] + c[3]*c[3];
      uq += __shfl_xor(uq, 16);
      uq += __shfl_xor(uq, 32);
      if (g == 0) usq[((size_t)o * NI + i) * NB + b] = uq;
      #pragma unroll
      for (int j = 0; j < 4; ++j) s0[bt][j] += c[j];
    }
  }
  #pragma unroll
  for (int bt = 0; bt < 4; ++bt){
    int b = (w * 4 + bt) * 16 + col;
    float4 v = make_float4(0.1f * s0[bt][0], 0.1f * s0[bt][1],
                           0.1f * s0[bt][2], 0.1f * s0[bt][3]);
    Pq[((size_t)(o * 4 + g) * PCH + ch) * NB + b] = v;
  }
}

// red: sum Pq over 144 ch (512 thr: two ch-halves + LDS combine).
// !LAST -> Sbt bf16 [o][b][d]; LAST -> Sq float4 [o][dq][b]
template<bool LAST>
__global__ __launch_bounds__(512) void k_red(const float4* __restrict__ Pq,
                                             u16* __restrict__ Sbt,
                                             float4* __restrict__ Sq){
  int o = blockIdx.x, dq = blockIdx.y;
  int half = threadIdx.x >> 8, b = threadIdx.x & 255;
  const float4* p = Pq + ((size_t)(o * 4 + dq) * PCH + half * 72) * NB + b;
  float4 a = make_float4(0.f, 0.f, 0.f, 0.f);
  #pragma unroll 8
  for (int ch = 0; ch < 72; ++ch){
    float4 v = p[(size_t)ch * NB];
    a.x += v.x; a.y += v.y; a.z += v.z; a.w += v.w;
  }
  __shared__ float4 tmp[256];
  if (half) tmp[b] = a;
  __syncthreads();
  if (!half){
    float4 v = tmp[b];
    a.x += v.x; a.y += v.y; a.z += v.z; a.w += v.w;
    if (LAST){
      Sq[((size_t)o * 4 + dq) * NB + b] = a;
    } else {
      uint2 pk = make_uint2(cvt_pk_bf16(a.x, a.y), cvt_pk_bf16(a.z, a.w));
      *(uint2*)(Sbt + ((size_t)o * NB + b) * ND + dq * 4) = pk;
    }
  }
}

// dotacc: per block (ch of 8 i, bq of 64 b): dot via MFMA(WTb,Sbt) -> db -> L -> softmax
// -> c (LDS) -> c-weighted MFMA accumulation -> Pq partial
template<bool FIRST>
__global__ __launch_bounds__(256) void k_dotacc(const u16* __restrict__ xbf,
                                                const u16* __restrict__ WTb,
                                                const u16* __restrict__ Wb,
                                                const u16* __restrict__ Sbt,
                                                const float* __restrict__ usq,
                                                float* __restrict__ L,
                                                float4* __restrict__ Pq){
  int ch = blockIdx.x, bq = blockIdx.y, i0 = ch * PIC;
  int w = threadIdx.x >> 6, l = threadIdx.x & 63, g = l >> 4, col = l & 15;
  int b = bq * 64 + w * 16 + col;

  __shared__ float c_lds[NO][PIC][66];   // padded: g-lanes hit distinct banks

  // S fragments + |S|^2
  s8v sb[NO];
  float s2v[NO];
  #pragma unroll
  for (int o = 0; o < NO; ++o){
    sb[o] = zero8();
    if (g < 2)
      sb[o] = *(const s8v*)(Sbt + ((size_t)o * NB + b) * ND + 8 * g);
    float s2 = 0.f;
    #pragma unroll
    for (int j = 0; j < 8; ++j){
      float v = bf2f((u16)sb[o][j]);
      s2 = fmaf(v, v, s2);
    }
    s2 += __shfl_xor(s2, 16);
    s2 += __shfl_xor(s2, 32);
    s2v[o] = s2;
  }

  // dot + softmax -> c into LDS
  for (int ip = 0; ip < PIC / 2; ++ip){
    int i0p = i0 + 2 * ip;
    int i = i0p + (g >> 1);
    int kb = 4 * (g & 1);
    ushort4 xq = *(const ushort4*)(xbf + ((size_t)i * NB + b) * NK + kb);
    float dots[NO];
    #pragma unroll
    for (int o = 0; o < NO; ++o){
      s8v a = zero8();
      if (g < 2){
        int ia = i0p + (col >> 3), ka = col & 7;
        a = *(const s8v*)(WTb + (((size_t)(o * NI + ia)) * NK + ka) * ND + 8 * g);
      }
      f4v c = {0.f, 0.f, 0.f, 0.f};
      c = __builtin_amdgcn_mfma_f32_16x16x32_bf16(a, sb[o], c, 0, 0, 0);
      float p = c[0] * bf2f(xq.x) + c[1] * bf2f(xq.y)
              + c[2] * bf2f(xq.z) + c[3] * bf2f(xq.w);
      p += __shfl_xor(p, 16);
      dots[o] = p;
    }
    float lg[NO];
    #pragma unroll
    for (int o = 0; o < NO; ++o){
      float us = usq[((size_t)o * NI + i) * NB + b];
      float t2 = fmaxf(s2v[o] - 2.f * dots[o] + us, 0.f);
      float ut = dots[o] - us;
      float db = (t2 / (1.f + t2)) * ut / (sqrtf(t2) + 1e-8f);
      float lo = FIRST ? db : (L[((size_t)o * NI + i) * NB + b] + db);
      if (FIRST && ((g & 1) == 0)) L[((size_t)o * NI + i) * NB + b] = lo;
      lg[o] = lo;
    }
    float m = lg[0];
    #pragma unroll
    for (int o = 1; o < NO; ++o) m = fmaxf(m, lg[o]);
    float den = 0.f;
    #pragma unroll
    for (int o = 0; o < NO; ++o){ lg[o] = __expf(lg[o] - m); den += lg[o]; }
    float inv = 1.f / den;
    if ((g & 1) == 0){
      int ii = 2 * ip + (g >> 1);
      #pragma unroll
      for (int o = 0; o < NO; ++o)
        c_lds[o][ii][w * 16 + col] = lg[o] * inv;
    }
  }
  __syncthreads();

  // acc: Pq[(o*4+g)*PCH+ch][b] = sum over this block's 8 i of c * u
  for (int o = 0; o < NO; ++o){
    f4v acc = {0.f, 0.f, 0.f, 0.f};
    #pragma unroll
    for (int kt = 0; kt < PIC / 4; ++kt){
      int il = i0 + kt * 4 + g;
      s8v a = *(const s8v*)(Wb + ((size_t)(o * NI + il) * ND + col) * NK);
      float cw = c_lds[o][kt * 4 + g][w * 16 + col];
      s8v xv = *(const s8v*)(xbf + ((size_t)il * NB + b) * NK);
      u32 q0 = cvt_pk_bf16(bf2f((u16)xv[0]) * cw, bf2f((u16)xv[1]) * cw);
      u32 q1 = cvt_pk_bf16(bf2f((u16)xv[2]) * cw, bf2f((u16)xv[3]) * cw);
      u32 q2 = cvt_pk_bf16(bf2f((u16)xv[4]) * cw, bf2f((u16)xv[5]) * cw);
      u32 q3 = cvt_pk_bf16(bf2f((u16)xv[6]) * cw, bf2f((u16)xv[7]) * cw);
      uint4 qq = make_uint4(q0, q1, q2, q3);
      s8v bb = __builtin_bit_cast(s8v, qq);
      acc = __builtin_amdgcn_mfma_f32_16x16x32_bf16(a, bb, acc, 0, 0, 0);
    }
    Pq[((size_t)(o * 4 + g) * PCH + ch) * NB + b] =
      make_float4(acc[0], acc[1], acc[2], acc[3]);
  }
}

// final: squash(S[o,:,b]) -> out[b][o][d]
__global__ __launch_bounds__(256) void k_final(const float4* __restrict__ Sq,
                                               float* __restrict__ out){
  int o = blockIdx.x, b = threadIdx.x;
  float4 sq[4];
  float s2 = 0.f;
  #pragma unroll
  for (int q = 0; q < 4; ++q){
    sq[q] = Sq[((size_t)o * 4 + q) * NB + b];
    s2 += sq[q].x * sq[q].x + sq[q].y * sq[q].y + sq[q].z * sq[q].z + sq[q].w * sq[q].w;
  }
  float sc = (s2 / (1.f + s2)) / (sqrtf(s2) + 1e-8f);
  #pragma unroll
  for (int q = 0; q < 4; ++q){
    float4 v = make_float4(sq[q].x * sc, sq[q].y * sc, sq[q].z * sc, sq[q].w * sc);
    *(float4*)(out + ((size_t)b * NO + o) * ND + 4 * q) = v;
  }
}

extern "C" void kernel_launch(void* const* d_in, const int* in_sizes, int n_in,
                              void* d_out, int out_size, void* d_ws, size_t ws_size,
                              hipStream_t stream){
  const float* x = (const float*)d_in[0];
  // d_in[1] (y) unused by the reference computation.
  const float* W = (const float*)d_in[2];
  float* out = (float*)d_out;
  char* ws = (char*)d_ws;

  const size_t xbf_b = (size_t)NI * NB * NK * sizeof(u16);             // 4.7 MB
  const size_t Wb_b  = (size_t)NO * NI * ND * NK * sizeof(u16);        // 2.95 MB
  const size_t usq_b = (size_t)NO * NI * NB * sizeof(float);           // 11.8 MB
  const size_t L_b   = usq_b;                                          // 11.8 MB
  const size_t Pq_b  = (size_t)NO * 4 * PCH * NB * sizeof(float4);     // 23.6 MB
  const size_t Sq_b  = (size_t)NO * 4 * NB * sizeof(float4);           // 160 KB
  const size_t Sbt_b = (size_t)NO * NB * ND * sizeof(u16);             // 80 KB

  size_t off = 0;
  u16*    xbf = (u16*)(ws + off);    off += xbf_b;
  u16*    Wb  = (u16*)(ws + off);    off += Wb_b;
  u16*    WTb = (u16*)(ws + off);    off += Wb_b;
  float*  usq = (float*)(ws + off);  off += usq_b;
  float*  L   = (float*)(ws + off);  off += L_b;
  float4* Pq  = (float4*)(ws + off); off += Pq_b;
  float4* Sq  = (float4*)(ws + off); off += Sq_b;
  u16*    Sbt = (u16*)(ws + off);    off += Sbt_b;
  (void)ws_size; (void)in_sizes; (void)n_in; (void)out_size;

  k_prep<<<dim3(1008), 256, 0, stream>>>(x, W, xbf, Wb, WTb);

  // iter 0: uniform c = 0.1 -> partials + usq
  k_pass0<<<dim3(PCH, NO), 256, 0, stream>>>(xbf, Wb, usq, Pq);
  k_red<false><<<dim3(NO, 4), 512, 0, stream>>>(Pq, Sbt, Sq);
  k_dotacc<true><<<dim3(PCH, 4), 256, 0, stream>>>(xbf, WTb, Wb, Sbt, usq, L, Pq);

  // iter 1
  k_red<false><<<dim3(NO, 4), 512, 0, stream>>>(Pq, Sbt, Sq);
  k_dotacc<false><<<dim3(PCH, 4), 256, 0, stream>>>(xbf, WTb, Wb, Sbt, usq, L, Pq);

  // iter 2: reduce final accumulation + squash
  k_red<true><<<dim3(NO, 4), 512, 0, stream>>>(Pq, Sbt, Sq);
  k_final<<<dim3(NO), 256, 0, stream>>>(Sq, out);
}

// Round 11
// 128.705 us; speedup vs baseline: 5.5622x; 1.0337x over previous
//
#include <hip/hip_runtime.h>

#define NB 256
#define NO 10
#define NI 1152
#define NK 8
#define ND 16
#define PCH 144   // i-chunks for pass0/dotacc (PIC=8)
#define PIC 8

typedef unsigned short u16;
typedef unsigned int u32;
typedef __attribute__((ext_vector_type(8))) short s8v;   // 8 bf16 (MFMA A/B frag)
typedef __attribute__((ext_vector_type(4))) float f4v;   // MFMA C/D frag

__device__ __forceinline__ float bf2f(u16 h){ return __uint_as_float(((u32)h) << 16); }
__device__ __forceinline__ u16 f2bf(float f){
  u32 u = __float_as_uint(f);
  return (u16)((u + 0x7FFFu + ((u >> 16) & 1u)) >> 16);  // RNE
}
__device__ __forceinline__ u32 cvt_pk_bf16(float lo, float hi){
  u32 r;
  asm("v_cvt_pk_bf16_f32 %0, %1, %2" : "=v"(r) : "v"(lo), "v"(hi));
  return r;
}
__device__ __forceinline__ s8v zero8(){
  s8v z;
  #pragma unroll
  for (int j = 0; j < 8; ++j) z[j] = 0;
  return z;
}

// prep: blocks [0,288): x [b][i][k] f32 -> xbf [i][b][k] bf16 via LDS 32x32 tile
//       blocks [288,1008): W [o][i][d][k] -> Wb (same layout) + WTb [o][i][k][d]
__global__ __launch_bounds__(256) void k_prep(const float* __restrict__ x,
                                              const float* __restrict__ W,
                                              u16* __restrict__ xbf,
                                              u16* __restrict__ Wb,
                                              u16* __restrict__ WTb){
  int blk = blockIdx.x;
  if (blk < 288){
    __shared__ __align__(16) u16 tile[32][33][8];
    int i0 = (blk >> 3) * 32, b0 = (blk & 7) * 32;
    int t = threadIdx.x;
    int bl = t >> 3, seg = t & 7;    // phase 1: thread = (b-local, 4-i segment)
    const float* src = x + ((size_t)(b0 + bl) * NI + (i0 + seg * 4)) * NK;
    #pragma unroll
    for (int q = 0; q < 4; ++q){
      float4 v0 = *(const float4*)(src + q * 8);
      float4 v1 = *(const float4*)(src + q * 8 + 4);
      *(uint4*)(&tile[seg * 4 + q][bl][0]) =
        make_uint4(cvt_pk_bf16(v0.x, v0.y), cvt_pk_bf16(v0.z, v0.w),
                   cvt_pk_bf16(v1.x, v1.y), cvt_pk_bf16(v1.z, v1.w));
    }
    __syncthreads();
    int il = t >> 3, sb2 = t & 7;    // phase 2: thread = (i-local, 4-b segment)
    u16* dst = xbf + ((size_t)(i0 + il) * NB + b0 + sb2 * 4) * NK;
    #pragma unroll
    for (int q = 0; q < 4; ++q)
      *(uint4*)(dst + q * 8) = *(const uint4*)(&tile[il][sb2 * 4 + q][0]);
  } else {
    int t = (blk - 288) * 256 + threadIdx.x;   // one (o,i,d) row of 8 k per thread
    if (t < NO * NI * ND){
      int oi = t >> 4, d = t & 15;
      const float* src = W + (size_t)t * NK;
      float4 v0 = *(const float4*)(src);
      float4 v1 = *(const float4*)(src + 4);
      u32 p0 = cvt_pk_bf16(v0.x, v0.y), p1 = cvt_pk_bf16(v0.z, v0.w);
      u32 p2 = cvt_pk_bf16(v1.x, v1.y), p3 = cvt_pk_bf16(v1.z, v1.w);
      *(uint4*)(Wb + (size_t)t * NK) = make_uint4(p0, p1, p2, p3);
      u16 e[8] = {(u16)(p0 & 0xffff), (u16)(p0 >> 16), (u16)(p1 & 0xffff), (u16)(p1 >> 16),
                  (u16)(p2 & 0xffff), (u16)(p2 >> 16), (u16)(p3 & 0xffff), (u16)(p3 >> 16)};
      #pragma unroll
      for (int k = 0; k < 8; ++k)
        WTb[((size_t)oi * NK + k) * ND + d] = e[k];
    }
  }
}

// pass0: u-tiles via MFMA; usq bf16 [o][i][b]; Pq[(o*4+g)*PCH+ch][b] = 4xbf16(0.1*sum_i u)
__global__ __launch_bounds__(256) void k_pass0(const u16* __restrict__ xbf,
                                               const u16* __restrict__ Wb,
                                               u16* __restrict__ usq,
                                               uint2* __restrict__ Pq){
  int ch = blockIdx.x, o = blockIdx.y, i0 = ch * PIC;
  int w = threadIdx.x >> 6, l = threadIdx.x & 63, g = l >> 4, col = l & 15;
  float s0[4][4];
  #pragma unroll
  for (int bt = 0; bt < 4; ++bt){
    #pragma unroll
    for (int j = 0; j < 4; ++j) s0[bt][j] = 0.f;
  }
  for (int ii = 0; ii < PIC; ++ii){
    int i = i0 + ii;
    s8v a = zero8();
    if (g == 0)  // A[d=col][k=j]
      a = *(const s8v*)(Wb + ((size_t)(o * NI + i) * ND + col) * NK);
    #pragma unroll
    for (int bt = 0; bt < 4; ++bt){
      int b = (w * 4 + bt) * 16 + col;
      s8v bf = zero8();
      if (g == 0)  // B[k=j][n=col] = x[i][b][j]
        bf = *(const s8v*)(xbf + ((size_t)i * NB + b) * NK);
      f4v c = {0.f, 0.f, 0.f, 0.f};
      c = __builtin_amdgcn_mfma_f32_16x16x32_bf16(a, bf, c, 0, 0, 0);
      float uq = c[0]*c[0] + c[1]*c[1] + c[2]*c[2] + c[3]*c[3];
      uq += __shfl_xor(uq, 16);
      uq += __shfl_xor(uq, 32);
      if (g == 0) usq[((size_t)o * NI + i) * NB + b] = f2bf(uq);
      #pragma unroll
      for (int j = 0; j < 4; ++j) s0[bt][j] += c[j];
    }
  }
  #pragma unroll
  for (int bt = 0; bt < 4; ++bt){
    int b = (w * 4 + bt) * 16 + col;
    uint2 v = make_uint2(cvt_pk_bf16(0.1f * s0[bt][0], 0.1f * s0[bt][1]),
                         cvt_pk_bf16(0.1f * s0[bt][2], 0.1f * s0[bt][3]));
    Pq[((size_t)(o * 4 + g) * PCH + ch) * NB + b] = v;
  }
}

// red: sum bf16 Pq over 144 ch (512 thr: two ch-halves + LDS combine).
// !LAST -> Sbt bf16 [o][b][d]; LAST -> Sq float4 [o][dq][b]
template<bool LAST>
__global__ __launch_bounds__(512) void k_red(const uint2* __restrict__ Pq,
                                             u16* __restrict__ Sbt,
                                             float4* __restrict__ Sq){
  int o = blockIdx.x, dq = blockIdx.y;
  int half = threadIdx.x >> 8, b = threadIdx.x & 255;
  const uint2* p = Pq + ((size_t)(o * 4 + dq) * PCH + half * 72) * NB + b;
  float4 a = make_float4(0.f, 0.f, 0.f, 0.f);
  #pragma unroll 8
  for (int ch = 0; ch < 72; ++ch){
    uint2 v = p[(size_t)ch * NB];
    a.x += bf2f((u16)(v.x & 0xffff));
    a.y += bf2f((u16)(v.x >> 16));
    a.z += bf2f((u16)(v.y & 0xffff));
    a.w += bf2f((u16)(v.y >> 16));
  }
  __shared__ float4 tmp[256];
  if (half) tmp[b] = a;
  __syncthreads();
  if (!half){
    float4 v = tmp[b];
    a.x += v.x; a.y += v.y; a.z += v.z; a.w += v.w;
    if (LAST){
      Sq[((size_t)o * 4 + dq) * NB + b] = a;
    } else {
      uint2 pk = make_uint2(cvt_pk_bf16(a.x, a.y), cvt_pk_bf16(a.z, a.w));
      *(uint2*)(Sbt + ((size_t)o * NB + b) * ND + dq * 4) = pk;
    }
  }
}

// dotacc: per block (ch of 8 i, bq of 64 b): dot via MFMA(WTb,Sbt) -> db -> L -> softmax
// -> c (LDS) -> c-weighted MFMA accumulation -> bf16 Pq partial
template<bool FIRST>
__global__ __launch_bounds__(256) void k_dotacc(const u16* __restrict__ xbf,
                                                const u16* __restrict__ WTb,
                                                const u16* __restrict__ Wb,
                                                const u16* __restrict__ Sbt,
                                                const u16* __restrict__ usq,
                                                float* __restrict__ L,
                                                uint2* __restrict__ Pq){
  int ch = blockIdx.x, bq = blockIdx.y, i0 = ch * PIC;
  int w = threadIdx.x >> 6, l = threadIdx.x & 63, g = l >> 4, col = l & 15;
  int b = bq * 64 + w * 16 + col;

  __shared__ float c_lds[NO][PIC][66];   // padded: g-lanes hit distinct banks

  // S fragments + |S|^2
  s8v sb[NO];
  float s2v[NO];
  #pragma unroll
  for (int o = 0; o < NO; ++o){
    sb[o] = zero8();
    if (g < 2)
      sb[o] = *(const s8v*)(Sbt + ((size_t)o * NB + b) * ND + 8 * g);
    float s2 = 0.f;
    #pragma unroll
    for (int j = 0; j < 8; ++j){
      float v = bf2f((u16)sb[o][j]);
      s2 = fmaf(v, v, s2);
    }
    s2 += __shfl_xor(s2, 16);
    s2 += __shfl_xor(s2, 32);
    s2v[o] = s2;
  }

  // dot + softmax -> c into LDS
  for (int ip = 0; ip < PIC / 2; ++ip){
    int i0p = i0 + 2 * ip;
    int i = i0p + (g >> 1);
    int kb = 4 * (g & 1);
    ushort4 xq = *(const ushort4*)(xbf + ((size_t)i * NB + b) * NK + kb);
    float dots[NO];
    #pragma unroll
    for (int o = 0; o < NO; ++o){
      s8v a = zero8();
      if (g < 2){
        int ia = i0p + (col >> 3), ka = col & 7;
        a = *(const s8v*)(WTb + (((size_t)(o * NI + ia)) * NK + ka) * ND + 8 * g);
      }
      f4v c = {0.f, 0.f, 0.f, 0.f};
      c = __builtin_amdgcn_mfma_f32_16x16x32_bf16(a, sb[o], c, 0, 0, 0);
      float p = c[0] * bf2f(xq.x) + c[1] * bf2f(xq.y)
              + c[2] * bf2f(xq.z) + c[3] * bf2f(xq.w);
      p += __shfl_xor(p, 16);
      dots[o] = p;
    }
    float lg[NO];
    #pragma unroll
    for (int o = 0; o < NO; ++o){
      float us = bf2f(usq[((size_t)o * NI + i) * NB + b]);
      float t2 = fmaxf(s2v[o] - 2.f * dots[o] + us, 0.f);
      float ut = dots[o] - us;
      float db = (t2 / (1.f + t2)) * ut / (sqrtf(t2) + 1e-8f);
      float lo = FIRST ? db : (L[((size_t)o * NI + i) * NB + b] + db);
      if (FIRST && ((g & 1) == 0)) L[((size_t)o * NI + i) * NB + b] = lo;
      lg[o] = lo;
    }
    float m = lg[0];
    #pragma unroll
    for (int o = 1; o < NO; ++o) m = fmaxf(m, lg[o]);
    float den = 0.f;
    #pragma unroll
    for (int o = 0; o < NO; ++o){ lg[o] = __expf(lg[o] - m); den += lg[o]; }
    float inv = 1.f / den;
    if ((g & 1) == 0){
      int ii = 2 * ip + (g >> 1);
      #pragma unroll
      for (int o = 0; o < NO; ++o)
        c_lds[o][ii][w * 16 + col] = lg[o] * inv;
    }
  }
  __syncthreads();

  // acc: Pq[(o*4+g)*PCH+ch][b] = 4xbf16( sum over this block's 8 i of c * u )
  // xv fragments are o-invariant: hoist out of the o-loop.
  s8v xv0 = *(const s8v*)(xbf + ((size_t)(i0 + g) * NB + b) * NK);
  s8v xv1 = *(const s8v*)(xbf + ((size_t)(i0 + 4 + g) * NB + b) * NK);
  for (int o = 0; o < NO; ++o){
    f4v acc = {0.f, 0.f, 0.f, 0.f};
    #pragma unroll
    for (int kt = 0; kt < PIC / 4; ++kt){
      int il = i0 + kt * 4 + g;
      s8v a = *(const s8v*)(Wb + ((size_t)(o * NI + il) * ND + col) * NK);
      float cw = c_lds[o][kt * 4 + g][w * 16 + col];
      s8v xv = kt ? xv1 : xv0;
      u32 q0 = cvt_pk_bf16(bf2f((u16)xv[0]) * cw, bf2f((u16)xv[1]) * cw);
      u32 q1 = cvt_pk_bf16(bf2f((u16)xv[2]) * cw, bf2f((u16)xv[3]) * cw);
      u32 q2 = cvt_pk_bf16(bf2f((u16)xv[4]) * cw, bf2f((u16)xv[5]) * cw);
      u32 q3 = cvt_pk_bf16(bf2f((u16)xv[6]) * cw, bf2f((u16)xv[7]) * cw);
      uint4 qq = make_uint4(q0, q1, q2, q3);
      s8v bb = __builtin_bit_cast(s8v, qq);
      acc = __builtin_amdgcn_mfma_f32_16x16x32_bf16(a, bb, acc, 0, 0, 0);
    }
    uint2 v = make_uint2(cvt_pk_bf16(acc[0], acc[1]), cvt_pk_bf16(acc[2], acc[3]));
    Pq[((size_t)(o * 4 + g) * PCH + ch) * NB + b] = v;
  }
}

// final: squash(S[o,:,b]) -> out[b][o][d]
__global__ __launch_bounds__(256) void k_final(const float4* __restrict__ Sq,
                                               float* __restrict__ out){
  int o = blockIdx.x, b = threadIdx.x;
  float4 sq[4];
  float s2 = 0.f;
  #pragma unroll
  for (int q = 0; q < 4; ++q){
    sq[q] = Sq[((size_t)o * 4 + q) * NB + b];
    s2 += sq[q].x * sq[q].x + sq[q].y * sq[q].y + sq[q].z * sq[q].z + sq[q].w * sq[q].w;
  }
  float sc = (s2 / (1.f + s2)) / (sqrtf(s2) + 1e-8f);
  #pragma unroll
  for (int q = 0; q < 4; ++q){
    float4 v = make_float4(sq[q].x * sc, sq[q].y * sc, sq[q].z * sc, sq[q].w * sc);
    *(float4*)(out + ((size_t)b * NO + o) * ND + 4 * q) = v;
  }
}

extern "C" void kernel_launch(void* const* d_in, const int* in_sizes, int n_in,
                              void* d_out, int out_size, void* d_ws, size_t ws_size,
                              hipStream_t stream){
  const float* x = (const float*)d_in[0];
  // d_in[1] (y) unused by the reference computation.
  const float* W = (const float*)d_in[2];
  float* out = (float*)d_out;
  char* ws = (char*)d_ws;

  const size_t xbf_b = (size_t)NI * NB * NK * sizeof(u16);             // 4.7 MB
  const size_t Wb_b  = (size_t)NO * NI * ND * NK * sizeof(u16);        // 2.95 MB
  const size_t usq_b = (size_t)NO * NI * NB * sizeof(u16);             // 5.9 MB
  const size_t L_b   = (size_t)NO * NI * NB * sizeof(float);           // 11.8 MB
  const size_t Pq_b  = (size_t)NO * 4 * PCH * NB * sizeof(uint2);      // 11.8 MB
  const size_t Sq_b  = (size_t)NO * 4 * NB * sizeof(float4);           // 160 KB
  const size_t Sbt_b = (size_t)NO * NB * ND * sizeof(u16);             // 80 KB

  size_t off = 0;
  u16*    xbf = (u16*)(ws + off);    off += xbf_b;
  u16*    Wb  = (u16*)(ws + off);    off += Wb_b;
  u16*    WTb = (u16*)(ws + off);    off += Wb_b;
  u16*    usq = (u16*)(ws + off);    off += usq_b;
  float*  L   = (float*)(ws + off);  off += L_b;
  uint2*  Pq  = (uint2*)(ws + off);  off += Pq_b;
  float4* Sq  = (float4*)(ws + off); off += Sq_b;
  u16*    Sbt = (u16*)(ws + off);    off += Sbt_b;
  (void)ws_size; (void)in_sizes; (void)n_in; (void)out_size;

  k_prep<<<dim3(1008), 256, 0, stream>>>(x, W, xbf, Wb, WTb);

  // iter 0: uniform c = 0.1 -> partials + usq
  k_pass0<<<dim3(PCH, NO), 256, 0, stream>>>(xbf, Wb, usq, Pq);
  k_red<false><<<dim3(NO, 4), 512, 0, stream>>>(Pq, Sbt, Sq);
  k_dotacc<true><<<dim3(PCH, 4), 256, 0, stream>>>(xbf, WTb, Wb, Sbt, usq, L, Pq);

  // iter 1
  k_red<false><<<dim3(NO, 4), 512, 0, stream>>>(Pq, Sbt, Sq);
  k_dotacc<false><<<dim3(PCH, 4), 256, 0, stream>>>(xbf, WTb, Wb, Sbt, usq, L, Pq);

  // iter 2: reduce final accumulation + squash
  k_red<true><<<dim3(NO, 4), 512, 0, stream>>>(Pq, Sbt, Sq);
  k_final<<<dim3(NO), 256, 0, stream>>>(Sq, out);
}